// Round 8
// baseline (5923.606 us; speedup 1.0000x reference)
//
#include <hip/hip_runtime.h>
#include <hip/hip_bf16.h>

// Collapsed-projector persistent-GRU kernel for MI355X.
// Round 8 = R6-proven per-group machinery, two batch groups per block with
// interleaved phases so each group's publish->gather visibility latency is
// hidden behind the other group's compute. 128 blocks x 256 threads.
// Tag-in-data sync (the gather IS the barrier); epilogues on w0 (A) / w1 (B).

#define HIDDEN 1024
#define INDIM  63
#define TSEQ   512
#define MB     16
#define NGRP   4
#define HWORDS 512          // 8B words per h row (2 cols each)

typedef __attribute__((ext_vector_type(8))) short bfrag8;  // 8 bf16 in 4 VGPRs
typedef __attribute__((ext_vector_type(4))) float ffrag4;  // MFMA accumulator
typedef unsigned long long ull;

#define MFMA_B16(a, b, c) __builtin_amdgcn_mfma_f32_16x16x32_bf16((a), (b), (c), 0, 0, 0)

__device__ __forceinline__ short f2bf(float x) {
  __hip_bfloat16 b = __float2bfloat16(x);
  return __builtin_bit_cast(short, b);
}
__device__ __forceinline__ float bf2f(short s) {
  unsigned u = ((unsigned)(unsigned short)s) << 16;
  return __builtin_bit_cast(float, u);
}

// ---------------- precompute kernels ----------------

__global__ void k_t1(const float* __restrict__ W2, const float* __restrict__ b1,
                     const float* __restrict__ b2, float* __restrict__ t1) {
  const int w = threadIdx.x >> 6, lane = threadIdx.x & 63;
  const int o = blockIdx.x * 4 + w;
  if (o >= HIDDEN) return;
  const float* row = W2 + (size_t)o * HIDDEN;
  float s = 0.f;
  for (int k = lane; k < HIDDEN; k += 64) s += row[k] * b1[k];
  for (int off = 32; off; off >>= 1) s += __shfl_down(s, off, 64);
  if (lane == 0) t1[o] = s + b2[o];
}

__global__ void k_bp(const float* __restrict__ W3, const float* __restrict__ t1,
                     const float* __restrict__ b3, float* __restrict__ bp) {
  const int w = threadIdx.x >> 6, lane = threadIdx.x & 63;
  for (int d = w; d < INDIM; d += 4) {
    const float* row = W3 + (size_t)d * HIDDEN;
    float s = 0.f;
    for (int k = lane; k < HIDDEN; k += 64) s += row[k] * t1[k];
    for (int off = 32; off; off >>= 1) s += __shfl_down(s, off, 64);
    if (lane == 0) bp[d] = s + b3[d];
  }
}

__global__ void k_gemm(const float* __restrict__ A, const float* __restrict__ B,
                       float* __restrict__ C, int M, int N, int K) {
  __shared__ float As[16][17], Bs[16][17];
  const int tx = threadIdx.x, ty = threadIdx.y;
  const int row = blockIdx.y * 16 + ty;
  const int col = blockIdx.x * 16 + tx;
  float acc = 0.f;
  for (int k0 = 0; k0 < K; k0 += 16) {
    As[ty][tx] = (row < M) ? A[(size_t)row * K + k0 + tx] : 0.f;
    Bs[ty][tx] = B[(size_t)(k0 + ty) * N + col];
    __syncthreads();
#pragma unroll
    for (int kk = 0; kk < 16; ++kk) acc += As[ty][kk] * Bs[kk][tx];
    __syncthreads();
  }
  if (row < M && col < N) C[(size_t)row * N + col] = acc;
}

// ---------------- main persistent kernel ----------------

__global__ __launch_bounds__(256, 1) void k_main(
    const float* __restrict__ X,
    const float* __restrict__ W_ih, const float* __restrict__ W_hh,
    const float* __restrict__ b_ih, const float* __restrict__ b_hh,
    const float* __restrict__ WpF, const float* __restrict__ bpF,
    const int* __restrict__ pCL, const int* __restrict__ pGT,
    ull* __restrict__ hb, float* __restrict__ OUT) {
  // per-group state, duplicated (A = group 2p, B = group 2p+1)
  __shared__ short h_stA[MB][HIDDEN + 8], h_stB[MB][HIDDEN + 8];
  __shared__ short inpbA[MB][88], inpbB[MB][88];
  __shared__ float inpfA[MB][68], inpfB[MB][68];
  __shared__ float tA[6][MB][17], tB[6][MB][17];  // r,z,hn,ir,iz,in tiles
  __shared__ short htA[MB][16], htB[MB][16];      // h repack for packed store

  const int tid = threadIdx.x;
  const int w = tid >> 6;
  const int lane = tid & 63;
  const int c = lane & 15;
  const int quad = lane >> 4;
  const int p = blockIdx.x >> 6;   // pair id 0..1
  const int j = blockIdx.x & 63;   // 16-col slice
  const int grpA = 2 * p, grpB = 2 * p + 1;

  const int gtv = pGT[0];
  int period = pCL[0] + gtv;
  if (period < 1) period = 1;

  // --- persistent register-resident weight fragments (group-independent) ---
  bfrag8 wB[32];
  bfrag8 wp[32];
  if (w < 3) {
    const float* wr = W_hh + ((size_t)w * HIDDEN + (size_t)j * 16 + c) * HIDDEN;
#pragma unroll
    for (int ks = 0; ks < 32; ++ks) {
      const float* pw = wr + ks * 32 + quad * 8;
      bfrag8 f;
#pragma unroll
      for (int e = 0; e < 8; ++e) f[e] = f2bf(pw[e]);
      wB[ks] = f;
    }
  } else {
#pragma unroll
    for (int gate = 0; gate < 3; ++gate) {
      const float* wr = W_ih + ((size_t)gate * HIDDEN + (size_t)j * 16 + c) * INDIM;
#pragma unroll
      for (int ks = 0; ks < 2; ++ks) {
        bfrag8 f;
#pragma unroll
        for (int e = 0; e < 8; ++e) {
          int k = ks * 32 + quad * 8 + e;
          f[e] = (k < INDIM) ? f2bf(wr[k]) : (short)0;
        }
        wB[gate * 2 + ks] = f;
      }
    }
  }
  const int dd = 16 * w + c;  // out column this lane produces
  {
    const float* wr = WpF + (size_t)dd * HIDDEN;
#pragma unroll
    for (int ks = 0; ks < 32; ++ks) {
      bfrag8 f;
#pragma unroll
      for (int e = 0; e < 8; ++e)
        f[e] = (dd < INDIM) ? f2bf(wr[ks * 32 + quad * 8 + e]) : (short)0;
      wp[ks] = f;
    }
  }

  float bias_g;
  if (w == 0)      bias_g = b_ih[j * 16 + c] + b_hh[j * 16 + c];
  else if (w == 1) bias_g = b_ih[HIDDEN + j * 16 + c] + b_hh[HIDDEN + j * 16 + c];
  else if (w == 2) bias_g = b_hh[2 * HIDDEN + j * 16 + c];
  else             bias_g = b_ih[2 * HIDDEN + j * 16 + c];
  const float bp_l = (dd < INDIM) ? bpF[dd] : 0.f;

  for (int i = tid; i < MB * (HIDDEN + 8); i += 256) {
    ((short*)h_stA)[i] = 0; ((short*)h_stB)[i] = 0;
  }
  for (int i = tid; i < MB * 88; i += 256) {
    ((short*)inpbA)[i] = 0; ((short*)inpbB)[i] = 0;
  }
  for (int i = tid; i < MB * 68; i += 256) {
    ((float*)inpfA)[i] = 0.f; ((float*)inpfB)[i] = 0.f;
  }

  // tagged h buffers: [2][NGRP][MB][HWORDS] ull
  ull* hbA[2] = {hb + (size_t)grpA * MB * HWORDS,
                 hb + (size_t)(NGRP + grpA) * MB * HWORDS};
  ull* hbB[2] = {hb + (size_t)grpB * MB * HWORDS,
                 hb + (size_t)(NGRP + grpB) * MB * HWORDS};

  for (int t = 0; t < TSEQ; ++t) {
    const unsigned tg = (unsigned)(t + 1);
    const bool teach = ((t % period) < gtv);
    const bool rep = (t + 1 < TSEQ) && !(((t + 1) % period) < gtv);

    if (teach) {
      const int row = tid >> 4, d0 = (tid & 15) * 4;
      const float* xa = X + ((size_t)(grpA * MB + row) * TSEQ + t) * INDIM;
      const float* xb = X + ((size_t)(grpB * MB + row) * TSEQ + t) * INDIM;
#pragma unroll
      for (int e = 0; e < 4; ++e) {
        int d = d0 + e;
        float va = (d < INDIM) ? xa[d] : 0.f;
        float vb = (d < INDIM) ? xb[d] : 0.f;
        inpfA[row][d] = va; inpbA[row][d] = f2bf(va);
        inpfB[row][d] = vb; inpbB[row][d] = f2bf(vb);
      }
    }
    __syncthreads();  // S1: inp ready; h_stA/B hold h(t-1)

    // ---- A-gates ----
    if (w < 3) {
      ffrag4 acc[4];
#pragma unroll
      for (int e = 0; e < 4; ++e) {
        acc[0][e] = bias_g; acc[1][e] = 0.f; acc[2][e] = 0.f; acc[3][e] = 0.f;
      }
#pragma unroll
      for (int ks = 0; ks < 32; ++ks) {
        const bfrag8 a = *(const bfrag8*)&h_stA[c][ks * 32 + quad * 8];
        acc[ks & 3] = MFMA_B16(a, wB[ks], acc[ks & 3]);
      }
      ffrag4 gs = acc[0] + acc[1] + acc[2] + acc[3];
#pragma unroll
      for (int i = 0; i < 4; ++i) tA[w][quad * 4 + i][c] = gs[i];
    } else {
      ffrag4 gir, giz, gin;
#pragma unroll
      for (int e = 0; e < 4; ++e) { gir[e] = 0.f; giz[e] = 0.f; gin[e] = bias_g; }
#pragma unroll
      for (int ks = 0; ks < 2; ++ks) {
        const bfrag8 a = *(const bfrag8*)&inpbA[c][ks * 32 + quad * 8];
        gir = MFMA_B16(a, wB[0 + ks], gir);
        giz = MFMA_B16(a, wB[2 + ks], giz);
        gin = MFMA_B16(a, wB[4 + ks], gin);
      }
#pragma unroll
      for (int i = 0; i < 4; ++i) {
        tA[3][quad * 4 + i][c] = gir[i];
        tA[4][quad * 4 + i][c] = giz[i];
        tA[5][quad * 4 + i][c] = gin[i];
      }
    }
    __syncthreads();  // S2: A tiles ready; h_stA dead until A-gather

    ull* hwA = hbA[t & 1];
    if (w == 0) {
      // A-epilogue + tagged publish (others proceed straight to B-gates)
#pragma unroll
      for (int i = 0; i < 4; ++i) {
        const int row = quad * 4 + i;
        float r = 1.f / (1.f + __expf(-(tA[0][row][c] + tA[3][row][c])));
        float z = 1.f / (1.f + __expf(-(tA[1][row][c] + tA[4][row][c])));
        float n = tanhf(tA[5][row][c] + r * tA[2][row][c]);
        float hp = bf2f(h_stA[row][j * 16 + c]);
        htA[row][c] = f2bf((1.f - z) * n + z * hp);
      }
      asm volatile("" ::: "memory");  // TBAA-safe: reads below htA stores
      const int r2 = lane >> 2, q4 = (lane & 3) * 4;
      unsigned lo0 = (unsigned)(unsigned short)htA[r2][q4 + 0] |
                     ((unsigned)(unsigned short)htA[r2][q4 + 1] << 16);
      unsigned lo1 = (unsigned)(unsigned short)htA[r2][q4 + 2] |
                     ((unsigned)(unsigned short)htA[r2][q4 + 3] << 16);
      ull* dst = hwA + (size_t)r2 * HWORDS + 8 * j + (lane & 3) * 2;
      __hip_atomic_store(dst, ((ull)tg << 32) | lo0,
                         __ATOMIC_RELAXED, __HIP_MEMORY_SCOPE_SYSTEM);
      __hip_atomic_store(dst + 1, ((ull)tg << 32) | lo1,
                         __ATOMIC_RELAXED, __HIP_MEMORY_SCOPE_SYSTEM);
    }

    // ---- B-gates (hides A's visibility latency; w0 joins late) ----
    if (w < 3) {
      ffrag4 acc[4];
#pragma unroll
      for (int e = 0; e < 4; ++e) {
        acc[0][e] = bias_g; acc[1][e] = 0.f; acc[2][e] = 0.f; acc[3][e] = 0.f;
      }
#pragma unroll
      for (int ks = 0; ks < 32; ++ks) {
        const bfrag8 a = *(const bfrag8*)&h_stB[c][ks * 32 + quad * 8];
        acc[ks & 3] = MFMA_B16(a, wB[ks], acc[ks & 3]);
      }
      ffrag4 gs = acc[0] + acc[1] + acc[2] + acc[3];
#pragma unroll
      for (int i = 0; i < 4; ++i) tB[w][quad * 4 + i][c] = gs[i];
    } else {
      ffrag4 gir, giz, gin;
#pragma unroll
      for (int e = 0; e < 4; ++e) { gir[e] = 0.f; giz[e] = 0.f; gin[e] = bias_g; }
#pragma unroll
      for (int ks = 0; ks < 2; ++ks) {
        const bfrag8 a = *(const bfrag8*)&inpbB[c][ks * 32 + quad * 8];
        gir = MFMA_B16(a, wB[0 + ks], gir);
        giz = MFMA_B16(a, wB[2 + ks], giz);
        gin = MFMA_B16(a, wB[4 + ks], gin);
      }
#pragma unroll
      for (int i = 0; i < 4; ++i) {
        tB[3][quad * 4 + i][c] = gir[i];
        tB[4][quad * 4 + i][c] = giz[i];
        tB[5][quad * 4 + i][c] = gin[i];
      }
    }
    __syncthreads();  // S4: B tiles ready; also orders A-publish before A-gather

    ull* hwB = hbB[t & 1];
    if (w == 1) {
      // B-epilogue + publish (overlaps others' A-gather)
#pragma unroll
      for (int i = 0; i < 4; ++i) {
        const int row = quad * 4 + i;
        float r = 1.f / (1.f + __expf(-(tB[0][row][c] + tB[3][row][c])));
        float z = 1.f / (1.f + __expf(-(tB[1][row][c] + tB[4][row][c])));
        float n = tanhf(tB[5][row][c] + r * tB[2][row][c]);
        float hp = bf2f(h_stB[row][j * 16 + c]);
        htB[row][c] = f2bf((1.f - z) * n + z * hp);
      }
      asm volatile("" ::: "memory");
      const int r2 = lane >> 2, q4 = (lane & 3) * 4;
      unsigned lo0 = (unsigned)(unsigned short)htB[r2][q4 + 0] |
                     ((unsigned)(unsigned short)htB[r2][q4 + 1] << 16);
      unsigned lo1 = (unsigned)(unsigned short)htB[r2][q4 + 2] |
                     ((unsigned)(unsigned short)htB[r2][q4 + 3] << 16);
      ull* dst = hwB + (size_t)r2 * HWORDS + 8 * j + (lane & 3) * 2;
      __hip_atomic_store(dst, ((ull)tg << 32) | lo0,
                         __ATOMIC_RELAXED, __HIP_MEMORY_SCOPE_SYSTEM);
      __hip_atomic_store(dst + 1, ((ull)tg << 32) | lo1,
                         __ATOMIC_RELAXED, __HIP_MEMORY_SCOPE_SYSTEM);
    }

    // ---- gather A: the load IS the barrier (retry until tag == t+1) ----
    {
      ull v[32];
#pragma unroll
      for (int s = 0; s < 32; ++s)
        v[s] = __hip_atomic_load(&hwA[tid + s * 256], __ATOMIC_RELAXED,
                                 __HIP_MEMORY_SCOPE_SYSTEM);
      bool bad = true;
      while (bad) {
        bad = false;
#pragma unroll
        for (int s = 0; s < 32; ++s) {
          if ((unsigned)(v[s] >> 32) != tg) {
            v[s] = __hip_atomic_load(&hwA[tid + s * 256], __ATOMIC_RELAXED,
                                     __HIP_MEMORY_SCOPE_SYSTEM);
            bad = true;
          }
        }
      }
#pragma unroll
      for (int s = 0; s < 32; ++s) {
        const int widx = tid + s * 256;  // 16 rows x 512 words
        *(unsigned*)&h_stA[widx >> 9][(widx & 511) * 2] = (unsigned)v[s];
      }
    }
    __syncthreads();  // S5: h_stA = hA(t)

    // ---- A out-proj: out = inp + h @ Wp^T + bp ----
    if (rep || j == 0) {
      ffrag4 oa0, oa1;
#pragma unroll
      for (int e = 0; e < 4; ++e) { oa0[e] = bp_l; oa1[e] = 0.f; }
#pragma unroll
      for (int ks = 0; ks < 32; ++ks) {
        const bfrag8 a = *(const bfrag8*)&h_stA[c][ks * 32 + quad * 8];
        if (ks & 1) oa1 = MFMA_B16(a, wp[ks], oa1);
        else        oa0 = MFMA_B16(a, wp[ks], oa0);
      }
      ffrag4 o = oa0 + oa1;
#pragma unroll
      for (int i = 0; i < 4; ++i) {
        const int row = quad * 4 + i;
        if (dd < INDIM) {
          float val = o[i] + inpfA[row][dd];
          if (j == 0) OUT[((size_t)(grpA * MB + row) * TSEQ + t) * INDIM + dd] = val;
          if (rep) { inpfA[row][dd] = val; inpbA[row][dd] = f2bf(val); }
        } else if (rep) {
          inpbA[row][dd] = 0;
        }
      }
    }

    // ---- gather B ----
    {
      ull v[32];
#pragma unroll
      for (int s = 0; s < 32; ++s)
        v[s] = __hip_atomic_load(&hwB[tid + s * 256], __ATOMIC_RELAXED,
                                 __HIP_MEMORY_SCOPE_SYSTEM);
      bool bad = true;
      while (bad) {
        bad = false;
#pragma unroll
        for (int s = 0; s < 32; ++s) {
          if ((unsigned)(v[s] >> 32) != tg) {
            v[s] = __hip_atomic_load(&hwB[tid + s * 256], __ATOMIC_RELAXED,
                                     __HIP_MEMORY_SCOPE_SYSTEM);
            bad = true;
          }
        }
      }
#pragma unroll
      for (int s = 0; s < 32; ++s) {
        const int widx = tid + s * 256;
        *(unsigned*)&h_stB[widx >> 9][(widx & 511) * 2] = (unsigned)v[s];
      }
    }
    __syncthreads();  // S6: h_stB = hB(t)

    // ---- B out-proj ----
    if (rep || j == 0) {
      ffrag4 oa0, oa1;
#pragma unroll
      for (int e = 0; e < 4; ++e) { oa0[e] = bp_l; oa1[e] = 0.f; }
#pragma unroll
      for (int ks = 0; ks < 32; ++ks) {
        const bfrag8 a = *(const bfrag8*)&h_stB[c][ks * 32 + quad * 8];
        if (ks & 1) oa1 = MFMA_B16(a, wp[ks], oa1);
        else        oa0 = MFMA_B16(a, wp[ks], oa0);
      }
      ffrag4 o = oa0 + oa1;
#pragma unroll
      for (int i = 0; i < 4; ++i) {
        const int row = quad * 4 + i;
        if (dd < INDIM) {
          float val = o[i] + inpfB[row][dd];
          if (j == 0) OUT[((size_t)(grpB * MB + row) * TSEQ + t) * INDIM + dd] = val;
          if (rep) { inpfB[row][dd] = val; inpbB[row][dd] = f2bf(val); }
        } else if (rep) {
          inpbB[row][dd] = 0;
        }
      }
    }
    __syncthreads();  // S7: B out-proj reads/writes done before next staging
  }
}

// ---------------- host ----------------

extern "C" void kernel_launch(void* const* d_in, const int* in_sizes, int n_in,
                              void* d_out, int out_size, void* d_ws, size_t ws_size,
                              hipStream_t stream) {
  const float* X    = (const float*)d_in[0];
  const float* W_ih = (const float*)d_in[1];
  const float* W_hh = (const float*)d_in[2];
  const float* b_ih = (const float*)d_in[3];
  const float* b_hh = (const float*)d_in[4];
  const float* W1   = (const float*)d_in[5];
  const float* b1   = (const float*)d_in[6];
  const float* W2   = (const float*)d_in[7];
  const float* b2   = (const float*)d_in[8];
  const float* W3   = (const float*)d_in[9];
  const float* b3   = (const float*)d_in[10];
  const int* pCL    = (const int*)d_in[11];
  const int* pGT    = (const int*)d_in[12];
  float* OUT = (float*)d_out;

  // layout: T2 aliases hb (dead before k_main; hb memset after)
  char* ws = (char*)d_ws;
  float* bp = (float*)(ws + 1024);        // 63 f32
  float* t1 = (float*)(ws + 2048);        // 1024 f32
  float* Wp = (float*)(ws + 8192);        // 63x1024 f32 (258048 B)
  float* T2 = (float*)(ws + 270336);      // 63x1024 f32 scratch (aliases hb)
  ull*   hb = (ull*)(ws + 270336);        // 2 x 4 x 16 x 512 ull = 512 KB
  if (ws_size < 795 * 1024) return;

  k_t1<<<256, 256, 0, stream>>>(W2, b1, b2, t1);
  k_gemm<<<dim3(64, 4), dim3(16, 16), 0, stream>>>(W3, W2, T2, INDIM, HIDDEN, HIDDEN);
  k_gemm<<<dim3(64, 4), dim3(16, 16), 0, stream>>>(T2, W1, Wp, INDIM, HIDDEN, HIDDEN);
  k_bp<<<1, 256, 0, stream>>>(W3, t1, b3, bp);
  hipMemsetAsync(hb, 0, 2 * NGRP * MB * HWORDS * sizeof(ull), stream);  // tags := 0
  k_main<<<128, 256, 0, stream>>>(X, W_ih, W_hh, b_ih, b_hh, Wp, bp, pCL, pGT, hb, OUT);
}